// Round 1
// baseline (173.989 us; speedup 1.0000x reference)
//
#include <hip/hip_runtime.h>

#define AP_STRIDE 164                 // per-wire A stride (floats); 164%32=4 -> distinct LDS banks per w
#define AP_TOTAL  (4*AP_STRIDE)       // 656
#define WS_SUMS   AP_TOTAL            // ws[656..663]: sum[4], sumsq[4]
#define WS_SS     (WS_SUMS + 8)       // ws[664..671]: scale[4], shift[4]

// packed-triangular row offsets (row i holds j=i..15, padded to multiple of 4 floats)
static constexpr int ROWOFF[16] = {0,16,32,48,64,76,88,100,112,120,128,136,144,148,152,156};
static constexpr int ROWL4[16]  = {4,4,4,4,3,3,3,3,2,2,2,2,1,1,1,1};

// ---------------------------------------------------------------------------
// k_pre: build U (weights-only part of the circuit), then A_w = Re(phase * U^dag Z_w U),
// packed triangular with off-diagonal doubled. Also zero the sum accumulators.
// ---------------------------------------------------------------------------
__global__ void k_pre(const float* __restrict__ W, float* __restrict__ ws){
  __shared__ float Ur[16][16];   // Ur[k][col]
  __shared__ float Uim[16][16];
  const int t = threadIdx.x;

  // zero packed A (incl. float4 pads) and the accumulators
  for (int k = t; k < AP_TOTAL; k += 256) ws[k] = 0.f;
  if (t < 8) ws[WS_SUMS + t] = 0.f;

  if (t < 16){
    // thread t evolves basis state e_t through the weighted layers -> column t of U
    float re[16], im[16];
    #pragma unroll
    for (int i = 0; i < 16; i++){ re[i] = 0.f; im[i] = 0.f; }
    re[t] = 1.f;

    #pragma unroll
    for (int l = 0; l < 2; l++){
      #pragma unroll
      for (int w = 0; w < 4; w++){
        const int m = 8 >> w;               // wire w lives at bit (3-w)
        const float* g = W + (l*4 + w)*3;
        // RX(g0): [[c,-is],[-is,c]]
        {
          float th = 0.5f*g[0], c = cosf(th), s = sinf(th);
          #pragma unroll
          for (int i0 = 0; i0 < 16; i0++) if (!(i0 & m)){
            int i1 = i0 | m;
            float a0r=re[i0], a0i=im[i0], a1r=re[i1], a1i=im[i1];
            re[i0] = c*a0r + s*a1i;  im[i0] = c*a0i - s*a1r;
            re[i1] = c*a1r + s*a0i;  im[i1] = c*a1i - s*a0r;
          }
        }
        // RY(g1): [[c,-s],[s,c]]
        {
          float th = 0.5f*g[1], c = cosf(th), s = sinf(th);
          #pragma unroll
          for (int i0 = 0; i0 < 16; i0++) if (!(i0 & m)){
            int i1 = i0 | m;
            float a0r=re[i0], a0i=im[i0], a1r=re[i1], a1i=im[i1];
            re[i0] = c*a0r - s*a1r;  im[i0] = c*a0i - s*a1i;
            re[i1] = s*a0r + c*a1r;  im[i1] = s*a0i + c*a1i;
          }
        }
        // RZ(g2): diag(c-is, c+is)
        {
          float th = 0.5f*g[2], c = cosf(th), s = sinf(th);
          #pragma unroll
          for (int i0 = 0; i0 < 16; i0++) if (!(i0 & m)){
            int i1 = i0 | m;
            float a0r=re[i0], a0i=im[i0], a1r=re[i1], a1i=im[i1];
            re[i0] = c*a0r + s*a0i;  im[i0] = c*a0i - s*a0r;
            re[i1] = c*a1r - s*a1i;  im[i1] = c*a1i + s*a1r;
          }
        }
      }
      // CNOT ring: for w: control w, target (w+1)%4 ; new[i] = old[bit(i,c) ? i^mt : i]
      #pragma unroll
      for (int w = 0; w < 4; w++){
        const int mc = 8 >> w, mt = 8 >> ((w+1)&3);
        float nr[16], ni[16];
        #pragma unroll
        for (int i = 0; i < 16; i++){
          int src = (i & mc) ? (i ^ mt) : i;
          nr[i] = re[src]; ni[i] = im[src];
        }
        #pragma unroll
        for (int i = 0; i < 16; i++){ re[i] = nr[i]; im[i] = ni[i]; }
      }
    }
    #pragma unroll
    for (int k = 0; k < 16; k++){ Ur[k][t] = re[k]; Uim[k][t] = im[k]; }
  }
  __syncthreads();   // also orders the zero-stores before the entry stores below

  // thread t -> (i,j); only i<=j writes. A_w[i,j] = Re(i^{p(i)-p(j)} * M_w[i,j])
  {
    const int i = t >> 4, j = t & 15;
    if (i <= j){
      const int d = (__popc(i) - __popc(j)) & 3;
      #pragma unroll
      for (int w = 0; w < 4; w++){
        const int zm = 8 >> w;
        float mr = 0.f, mi = 0.f;
        #pragma unroll
        for (int k = 0; k < 16; k++){
          float z = (k & zm) ? -1.f : 1.f;
          float uir = Ur[k][i], uii = Uim[k][i];
          float ujr = Ur[k][j], uji = Uim[k][j];
          mr += z*(uir*ujr + uii*uji);
          mi += z*(uir*uji - uii*ujr);
        }
        float v = (d == 0) ? mr : (d == 1) ? -mi : (d == 2) ? -mr : mi;
        if (i != j) v *= 2.f;               // fold symmetry into packed entry
        ws[w*AP_STRIDE + ROWOFF[i] + (j - i)] = v;
      }
    }
  }
}

// ---------------------------------------------------------------------------
// k_main: per block = 64 batch elements. Stage x into LDS, pool, cos/sin,
// quadratic forms, write q to d_out, accumulate sum/sumsq.
// ---------------------------------------------------------------------------
__global__ __launch_bounds__(256) void k_main(const float* __restrict__ x,
                                              const float* __restrict__ Ap,
                                              float* __restrict__ qout,
                                              float* __restrict__ sums){
  __shared__ __align__(16) float xs[64*148];     // row stride 148 (148%32=20 -> <=2-way conflicts)
  __shared__ __align__(16) float Asm[AP_TOTAL];
  __shared__ __align__(16) float csn[64][8];     // c[4], s[4] per local b
  __shared__ float wred[4][8];
  const int t = threadIdx.x;
  const size_t base = (size_t)blockIdx.x * 64;

  for (int k = t; k < AP_TOTAL; k += 256) Asm[k] = Ap[k];

  // stage 64 rows x 144 floats = 2304 float4, coalesced
  const float4* xg = (const float4*)(x + base*144);
  #pragma unroll
  for (int k = 0; k < 9; k++){
    int idx = t + k*256;
    int b  = idx / 36;          // 36 float4 per row
    int off = idx - b*36;
    *((float4*)(xs + b*148 + off*4)) = xg[idx];
  }
  __syncthreads();

  const int b = t >> 2, w = t & 3;

  // pooling: 6x6 block (r2=w>>1, c2=w&1), float2 LDS reads (all offsets even)
  {
    const float* xrow = xs + b*148 + (w >> 1)*72 + (w & 1)*6;
    float sum = 0.f;
    #pragma unroll
    for (int r = 0; r < 6; r++){
      const float2* p2 = (const float2*)(xrow + r*12);
      float2 u0 = p2[0], u1 = p2[1], u2 = p2[2];
      sum += (u0.x + u0.y) + (u1.x + u1.y) + (u2.x + u2.y);
    }
    float ang = sum * (0.5f/36.f);          // half-angle of pooled mean
    csn[b][w]   = cosf(ang);
    csn[b][w+4] = sinf(ang);
  }
  __syncthreads();

  // r vector: r_i = prod_w (bit(i,w) ? s_w : c_w), bit(i,w) = (i>>(3-w))&1
  float4 cc = *((const float4*)&csn[b][0]);
  float4 ss4 = *((const float4*)&csn[b][4]);
  const float cw[4] = {cc.x, cc.y, cc.z, cc.w};
  const float sw[4] = {ss4.x, ss4.y, ss4.z, ss4.w};
  float r[20];
  r[16] = r[17] = r[18] = r[19] = 0.f;
  #pragma unroll
  for (int i = 0; i < 16; i++){
    float v = ((i >> 3) & 1) ? sw[0] : cw[0];
    v *= ((i >> 2) & 1) ? sw[1] : cw[1];
    v *= ((i >> 1) & 1) ? sw[2] : cw[2];
    v *= (i & 1)        ? sw[3] : cw[3];
    r[i] = v;
  }

  // q_w = r^T A_w r  (packed upper-triangular, off-diag pre-doubled, zero pads)
  const float* Aw = Asm + w*AP_STRIDE;
  float q = 0.f;
  #pragma unroll
  for (int i = 0; i < 16; i++){
    float acc = 0.f;
    const float4* row4 = (const float4*)(Aw + ROWOFF[i]);
    #pragma unroll
    for (int mm = 0; mm < ROWL4[i]; mm++){
      float4 a = row4[mm];
      acc = fmaf(a.x, r[i + mm*4 + 0], acc);
      acc = fmaf(a.y, r[i + mm*4 + 1], acc);
      acc = fmaf(a.z, r[i + mm*4 + 2], acc);
      acc = fmaf(a.w, r[i + mm*4 + 3], acc);
    }
    q = fmaf(r[i], acc, q);
  }

  qout[base*4 + t] = q;                     // coalesced: out[(base+b)*4 + w]

  // reduce sum / sumsq per wire: lanes {w, w+4, ..., w+60}
  float qs = q, q2 = q*q;
  #pragma unroll
  for (int off = 32; off >= 4; off >>= 1){
    qs += __shfl_down(qs, off, 64);
    q2 += __shfl_down(q2, off, 64);
  }
  const int lane = t & 63, wv = t >> 6;
  if (lane < 4){ wred[wv][lane] = qs; wred[wv][lane+4] = q2; }
  __syncthreads();
  if (t < 8){
    float v = wred[0][t] + wred[1][t] + wred[2][t] + wred[3][t];
    atomicAdd(&sums[t], v);
  }
}

// ---------------------------------------------------------------------------
__global__ void k_stats(const float* __restrict__ sums,
                        const float* __restrict__ gamma,
                        const float* __restrict__ beta,
                        float* __restrict__ ss, float Bf){
  int t = threadIdx.x;
  if (t < 4){
    float invB = 1.f / Bf;
    float mean = sums[t] * invB;
    float var  = sums[t+4] * invB - mean*mean;
    float scale = gamma[t] * rsqrtf(var + 1e-5f);
    ss[t]   = scale;
    ss[t+4] = beta[t] - mean*scale;
  }
}

__global__ __launch_bounds__(256) void k_norm(float* __restrict__ out,
                                              const float* __restrict__ ss, int B){
  int idx = blockIdx.x*256 + threadIdx.x;    // one batch element (float4 of out)
  if (idx >= B) return;
  float4 sc = *((const float4*)ss);
  float4 sh = *((const float4*)(ss + 4));
  float4* o4 = (float4*)out;
  float4 v = o4[idx];
  v.x = fmaf(v.x, sc.x, sh.x);
  v.y = fmaf(v.y, sc.y, sh.y);
  v.z = fmaf(v.z, sc.z, sh.z);
  v.w = fmaf(v.w, sc.w, sh.w);
  o4[idx] = v;
}

// ---------------------------------------------------------------------------
extern "C" void kernel_launch(void* const* d_in, const int* in_sizes, int n_in,
                              void* d_out, int out_size, void* d_ws, size_t ws_size,
                              hipStream_t stream){
  const float* x     = (const float*)d_in[0];
  const float* W     = (const float*)d_in[1];
  const float* gamma = (const float*)d_in[2];
  const float* beta  = (const float*)d_in[3];
  float* ws  = (float*)d_ws;
  float* out = (float*)d_out;
  const int B = in_sizes[0] / 144;

  k_pre<<<1, 256, 0, stream>>>(W, ws);
  k_main<<<B/64, 256, 0, stream>>>(x, ws, out, ws + WS_SUMS);
  k_stats<<<1, 64, 0, stream>>>(ws + WS_SUMS, gamma, beta, ws + WS_SS, (float)B);
  k_norm<<<(B + 255)/256, 256, 0, stream>>>(out, ws + WS_SS, B);
}